// Round 1
// baseline (5896.811 us; speedup 1.0000x reference)
//
#include <hip/hip_runtime.h>
#include <cstdint>
#include <cstddef>

// Sizes (fixed by the problem)
#define B_ 256
#define S_ 128
#define F_ 128
#define H_ 512
#define C_ 64
#define L_ 16
// 4H = 2048, 3H = 1536

typedef __attribute__((ext_vector_type(8))) short short8;   // 8 x bf16 (4 VGPRs) MFMA A/B frag
typedef __attribute__((ext_vector_type(4))) float f4;       // MFMA C/D frag
typedef __attribute__((ext_vector_type(4))) unsigned int u4;

__device__ __forceinline__ unsigned short f2bf(float f) {   // fp32 -> bf16 RNE
  union { float f; unsigned u; } v; v.f = f;
  unsigned r = v.u + 0x7fffu + ((v.u >> 16) & 1u);
  return (unsigned short)(r >> 16);
}
__device__ __forceinline__ float sigmoid_(float x) { return 1.0f / (1.0f + __expf(-x)); }
__device__ __forceinline__ float tanh_(float x) {
  x = fminf(15.f, fmaxf(-15.f, x));           // clamp: avoid inf/inf
  float e = __expf(2.f * x);
  return (e - 1.f) / (e + 1.f);
}

// ---------------------------------------------------------------------------
// Pre-pack W_hh / W_ih into MFMA B-fragment order (bf16) + combined bias.
// Wpk row r = (ht*4+g)*16 + kit, 64 lanes x 8 elems: B[k][n], k = kit*32+(lane>>4)*8+j,
// n(col) = g*512 + ht*16 + (lane&15).
// ---------------------------------------------------------------------------
__global__ void prepack_w(const float* __restrict__ W_hh, const float* __restrict__ W_ih,
                          const float* __restrict__ b_ih, const float* __restrict__ b_hh,
                          unsigned short* __restrict__ Wpk, unsigned short* __restrict__ Wipk,
                          float* __restrict__ bc) {
  int t = blockIdx.x * blockDim.x + threadIdx.x;
  if (t < 131072) {                      // W_hh: 32 ht * 4 g * 16 kit * 64 lanes
    int lane = t & 63, row = t >> 6;
    int kit = row & 15, gh = row >> 4;
    int g = gh & 3, ht = gh >> 2;
    int k0 = kit * 32 + ((lane >> 4) << 3);
    int col = g * 512 + ht * 16 + (lane & 15);
#pragma unroll
    for (int j = 0; j < 8; j++)
      Wpk[t * 8 + j] = f2bf(W_hh[(k0 + j) * 2048 + col]);
  } else if (t < 131072 + 32768) {       // W_ih: 32 ht * 4 g * 4 kit * 64 lanes
    int t2 = t - 131072;
    int lane = t2 & 63, row = t2 >> 6;
    int kit = row & 3, gh = row >> 2;
    int g = gh & 3, ht = gh >> 2;
    int k0 = kit * 32 + ((lane >> 4) << 3);
    int col = g * 512 + ht * 16 + (lane & 15);
#pragma unroll
    for (int j = 0; j < 8; j++)
      Wipk[t2 * 8 + j] = f2bf(W_ih[(k0 + j) * 2048 + col]);
  } else if (t < 131072 + 32768 + 2048) {
    int i = t - 131072 - 32768;
    bc[i] = b_ih[i] + b_hh[i];           // b_ih + b_hh folded together
  }
}

// ---------------------------------------------------------------------------
// Pre-pack x into fragment-major bf16: xfr[((s*16+Rg)*16+kb)*128 + m*8 + sub],
// Rg = b>>4, m = b&15, kb = f>>3, sub = f&7. One thread per 8-elem chunk.
// ---------------------------------------------------------------------------
__global__ void prepack_x(const float* __restrict__ x, unsigned short* __restrict__ xfr) {
  int o8 = blockIdx.x * blockDim.x + threadIdx.x;   // 524288 chunks
  int m = o8 & 15, kb = (o8 >> 4) & 15, Rg = (o8 >> 8) & 15, s = o8 >> 12;
  int b = Rg * 16 + m;
  const float* src = x + (b * S_ + s) * F_ + kb * 8;
  unsigned short* dst = xfr + o8 * 8;
#pragma unroll
  for (int j = 0; j < 8; j++) dst[j] = f2bf(src[j]);
}

// ---------------------------------------------------------------------------
// Context gate, stage 1: hid1 = relu(context @ cg_w1 + cg_b1)   [256 x 512]
// ---------------------------------------------------------------------------
__global__ void ctx1_kernel(const float* __restrict__ context, const float* __restrict__ w1,
                            const float* __restrict__ b1, float* __restrict__ hid1) {
  __shared__ float cc[C_];
  int b = blockIdx.x, t = threadIdx.x;
  if (t < C_) cc[t] = context[b * C_ + t];
  __syncthreads();
  for (int j = t; j < H_; j += 256) {
    float acc = b1[j];
#pragma unroll 8
    for (int k = 0; k < C_; k++) acc = fmaf(cc[k], w1[k * H_ + j], acc);
    hid1[b * H_ + j] = fmaxf(acc, 0.f);
  }
}

// ---------------------------------------------------------------------------
// Context gate, stage 2: ctxg = sigmoid(hid1 @ cg_w2 + cg_b2)   [256 x 1536]
// 64 blocks, 4 rows each (reuses w2 across rows to cut L2 traffic 4x).
// ---------------------------------------------------------------------------
__global__ void ctx2_kernel(const float* __restrict__ hid1, const float* __restrict__ w2,
                            const float* __restrict__ b2, float* __restrict__ ctxg) {
  __shared__ float hr[4 * H_];
  int r0 = blockIdx.x * 4, t = threadIdx.x;
  for (int i = t; i < 4 * H_; i += 256) hr[i] = hid1[r0 * H_ + i];
  __syncthreads();
  float acc[4][6];
#pragma unroll
  for (int r = 0; r < 4; r++)
#pragma unroll
    for (int i = 0; i < 6; i++) acc[r][i] = 0.f;
  for (int k = 0; k < H_; k++) {
    float w[6];
#pragma unroll
    for (int i = 0; i < 6; i++) w[i] = w2[k * 1536 + t + i * 256];
#pragma unroll
    for (int r = 0; r < 4; r++) {
      float hv = hr[r * H_ + k];
#pragma unroll
      for (int i = 0; i < 6; i++) acc[r][i] = fmaf(hv, w[i], acc[r][i]);
    }
  }
#pragma unroll
  for (int r = 0; r < 4; r++)
#pragma unroll
    for (int i = 0; i < 6; i++) {
      int col = t + i * 256;
      ctxg[(r0 + r) * 1536 + col] = sigmoid_(acc[r][i] + b2[col]);
    }
}

// ---------------------------------------------------------------------------
// Persistent LSTM kernel. Grid = 256 blocks (8 batch-tiles x 32 h-col tiles),
// 256 threads (4 waves; wave g owns gate g). W frags resident in VGPRs.
// Per step: stage h (32 KB) + x (8 KB) to LDS (fragment-major, conflict-free
// b128 reads), 40 MFMAs/wave, cross-gate combine via LDS, elementwise update
// (c,h fp32 in registers), h->global bf16 (double-buffered), per-group
// (32-block) arrival-counter barrier.
// ---------------------------------------------------------------------------
__global__ void __launch_bounds__(256) lstm_kernel(
    const unsigned short* __restrict__ xfr, const unsigned short* __restrict__ Wpk,
    const unsigned short* __restrict__ Wipk, const float* __restrict__ bc,
    const float* __restrict__ ctxg, float* __restrict__ hfinal,
    unsigned short* __restrict__ hb0, unsigned short* __restrict__ hb1,
    unsigned int* __restrict__ ctr) {
  __shared__ __align__(16) unsigned short lds_h[16384];  // 2R x 64kb x 16m x 8  (32 KB)
  __shared__ __align__(16) unsigned short lds_x[4096];   // 2R x 4kit x 512      (8 KB)
  __shared__ float lds_g[2048];                          // 4g x 32b x 16j       (8 KB)

  int tid = threadIdx.x, lane = tid & 63, wid = tid >> 6;
  int bt = blockIdx.x >> 5, ht = blockIdx.x & 31;

  // --- prologue: resident weight fragments (coalesced 16B/lane loads) ---
  short8 wf[16], wfi[4];
  {
    const short8* wp = (const short8*)Wpk + (ht * 4 + wid) * 16 * 64 + lane;
#pragma unroll
    for (int kit = 0; kit < 16; kit++) wf[kit] = wp[kit * 64];
    const short8* wip = (const short8*)Wipk + (ht * 4 + wid) * 4 * 64 + lane;
#pragma unroll
    for (int kit = 0; kit < 4; kit++) wfi[kit] = wip[kit * 64];
  }

  // --- per-thread elementwise state: 2 (b,j) pairs, c kept fp32 in regs ---
  float cst[2] = {0.f, 0.f};
  float ci_[2], cf_[2], co_[2], bi_[2], bf_[2], bg_[2], bo_[2];
  int hoff[2], bglob[2], jglob[2];
#pragma unroll
  for (int p = 0; p < 2; p++) {
    int idx = tid + p * 256;
    int bl = idx >> 4, jl = idx & 15;
    int b = bt * 32 + bl, j = ht * 16 + jl;
    bglob[p] = b; jglob[p] = j;
    ci_[p] = ctxg[b * 1536 + j];
    cf_[p] = ctxg[b * 1536 + 512 + j];
    co_[p] = ctxg[b * 1536 + 1024 + j];
    bi_[p] = bc[j]; bf_[p] = bc[512 + j]; bg_[p] = bc[1024 + j]; bo_[p] = bc[1536 + j];
    hoff[p] = ((b >> 4) * 64 + (j >> 3)) * 128 + (b & 15) * 8 + (j & 7);  // fragment-major
  }

  for (int t = 0; t < S_; t++) {
    const unsigned short* hread = (t & 1) ? hb1 : hb0;   // double buffer
    unsigned short* hwrite = (t & 1) ? hb0 : hb1;

    // --- stage x-tile (2 chunks/wave) + h-tile (8 chunks/wave); 1 KB chunks ---
#pragma unroll
    for (int i = 0; i < 2; i++) {
      int c = wid * 2 + i, R = c >> 2, kit = c & 3;
      u4 d = *(const u4*)(xfr + (size_t)(((t * 16) + bt * 2 + R) * 16 + kit * 4) * 128 + lane * 8);
      *(u4*)(lds_x + (R * 4 + kit) * 512 + lane * 8) = d;
    }
#pragma unroll
    for (int i = 0; i < 8; i++) {
      int c = wid * 8 + i, R = c >> 4, kit = c & 15;
      u4 d = *(const u4*)(hread + (size_t)((bt * 2 + R) * 64 + kit * 4) * 128 + lane * 8);
      *(u4*)(lds_h + R * 8192 + kit * 512 + lane * 8) = d;
    }
    __syncthreads();

    // --- MFMA: gates(32x64) = x_t(32x128)@Wih_slice + h(32x512)@Whh_slice ---
    f4 acc0 = {0.f, 0.f, 0.f, 0.f}, acc1 = {0.f, 0.f, 0.f, 0.f};
#pragma unroll
    for (int kit = 0; kit < 4; kit++) {
      short8 a0 = *(const short8*)(lds_x + kit * 512 + lane * 8);
      short8 a1 = *(const short8*)(lds_x + 2048 + kit * 512 + lane * 8);
      acc0 = __builtin_amdgcn_mfma_f32_16x16x32_bf16(a0, wfi[kit], acc0, 0, 0, 0);
      acc1 = __builtin_amdgcn_mfma_f32_16x16x32_bf16(a1, wfi[kit], acc1, 0, 0, 0);
    }
#pragma unroll
    for (int kit = 0; kit < 16; kit++) {
      short8 a0 = *(const short8*)(lds_h + kit * 512 + lane * 8);
      short8 a1 = *(const short8*)(lds_h + 8192 + kit * 512 + lane * 8);
      acc0 = __builtin_amdgcn_mfma_f32_16x16x32_bf16(a0, wf[kit], acc0, 0, 0, 0);
      acc1 = __builtin_amdgcn_mfma_f32_16x16x32_bf16(a1, wf[kit], acc1, 0, 0, 0);
    }

    // --- cross-gate combine: wave g publishes its gate block to LDS ---
    {
      int q = lane >> 4, n = lane & 15;
#pragma unroll
      for (int r = 0; r < 4; r++) {
        lds_g[(wid * 32 + q * 4 + r) * 16 + n] = acc0[r];        // rows 0..15
        lds_g[(wid * 32 + 16 + q * 4 + r) * 16 + n] = acc1[r];   // rows 16..31
      }
    }
    __syncthreads();

    // --- elementwise LSTM cell update (fp32), write h bf16 fragment-major ---
#pragma unroll
    for (int p = 0; p < 2; p++) {
      int idx = tid + p * 256, bl = idx >> 4, jl = idx & 15;
      float gi = lds_g[(0 * 32 + bl) * 16 + jl] + bi_[p];
      float gf = lds_g[(1 * 32 + bl) * 16 + jl] + bf_[p];
      float gg = lds_g[(2 * 32 + bl) * 16 + jl] + bg_[p];
      float go = lds_g[(3 * 32 + bl) * 16 + jl] + bo_[p];
      float iv = ci_[p] * sigmoid_(gi);
      float fv = cf_[p] * sigmoid_(gf);
      float ov = co_[p] * sigmoid_(go);
      float gv = tanh_(gg);
      float c = fv * cst[p] + iv * gv;
      cst[p] = c;
      float h = ov * tanh_(c);
      hwrite[hoff[p]] = f2bf(h);
      if (t == S_ - 1) hfinal[bglob[p] * H_ + jglob[p]] = h;  // fp32 for the VAE head
    }

    // --- inter-block barrier (per batch-tile group of 32 blocks) ---
    if (t < S_ - 1) {
      __threadfence();            // h stores visible agent-wide
      __syncthreads();            // all threads' stores+fences done before arrive
      if (tid == 0) {
        unsigned int* c32 = ctr + (t * 8 + bt) * 16;   // 64B-spaced per-step counter
        __hip_atomic_fetch_add(c32, 1u, __ATOMIC_RELEASE, __HIP_MEMORY_SCOPE_AGENT);
        while (__hip_atomic_load(c32, __ATOMIC_ACQUIRE, __HIP_MEMORY_SCOPE_AGENT) < 32u) {
          __builtin_amdgcn_s_sleep(2);
        }
      }
      __syncthreads();
      __threadfence();            // per-wave acquire: invalidate caches before re-reading h
    }
  }
}

// ---------------------------------------------------------------------------
// VAE head: mu/lv = h@W + b, z = mu + eps*exp(0.5*lv),
// recon = relu(z@dec_w1+db1)@dec_w2+db2. One block per batch row, all fp32.
// ---------------------------------------------------------------------------
__global__ void post_kernel(const float* __restrict__ hfinal, const float* __restrict__ eps,
                            const float* __restrict__ mu_w, const float* __restrict__ mu_b,
                            const float* __restrict__ lv_w, const float* __restrict__ lv_b,
                            const float* __restrict__ dw1, const float* __restrict__ db1,
                            const float* __restrict__ dw2, const float* __restrict__ db2,
                            float* __restrict__ out) {
  __shared__ float sh[H_], sh1[H_], smu[L_], slv[L_], sz[L_];
  int b = blockIdx.x, t = threadIdx.x;
  for (int i = t; i < H_; i += 256) sh[i] = hfinal[b * H_ + i];
  __syncthreads();
  {
    int o = t >> 3, sub = t & 7, l = o & 15;   // 32 outputs x 8-lane partial dots
    const float* w = (o < 16) ? mu_w : lv_w;
    float acc = 0.f;
    int k0 = sub * 64;
#pragma unroll 8
    for (int k = k0; k < k0 + 64; k++) acc = fmaf(sh[k], w[k * L_ + l], acc);
#pragma unroll
    for (int d = 4; d >= 1; d >>= 1) acc += __shfl_down(acc, d, 8);
    if (sub == 0) {
      if (o < 16) { float v = acc + mu_b[l]; smu[l] = v; out[32768 + b * 16 + l] = v; }
      else        { float v = acc + lv_b[l]; slv[l] = v; out[36864 + b * 16 + l] = v; }
    }
  }
  __syncthreads();
  if (t < L_) sz[t] = smu[t] + eps[b * L_ + t] * __expf(0.5f * slv[t]);
  __syncthreads();
  for (int j = t; j < H_; j += 256) {
    float acc = db1[j];
#pragma unroll
    for (int l = 0; l < L_; l++) acc = fmaf(sz[l], dw1[l * H_ + j], acc);
    sh1[j] = fmaxf(acc, 0.f);
  }
  __syncthreads();
  if (t < F_) {
    float acc = db2[t];
    for (int k = 0; k < H_; k++) acc = fmaf(sh1[k], dw2[k * F_ + t], acc);
    out[b * F_ + t] = acc;
  }
}

// ---------------------------------------------------------------------------
extern "C" void kernel_launch(void* const* d_in, const int* in_sizes, int n_in,
                              void* d_out, int out_size, void* d_ws, size_t ws_size,
                              hipStream_t stream) {
  const float* x      = (const float*)d_in[0];
  const float* ctxin  = (const float*)d_in[1];
  const float* eps    = (const float*)d_in[2];
  const float* W_ih   = (const float*)d_in[3];
  const float* b_ih   = (const float*)d_in[4];
  const float* W_hh   = (const float*)d_in[5];
  const float* b_hh   = (const float*)d_in[6];
  const float* cg_w1  = (const float*)d_in[7];
  const float* cg_b1  = (const float*)d_in[8];
  const float* cg_w2  = (const float*)d_in[9];
  const float* cg_b2  = (const float*)d_in[10];
  const float* mu_w   = (const float*)d_in[11];
  const float* mu_b   = (const float*)d_in[12];
  const float* lv_w   = (const float*)d_in[13];
  const float* lv_b   = (const float*)d_in[14];
  const float* dec_w1 = (const float*)d_in[15];
  const float* dec_b1 = (const float*)d_in[16];
  const float* dec_w2 = (const float*)d_in[17];
  const float* dec_b2 = (const float*)d_in[18];
  float* out = (float*)d_out;

  char* ws = (char*)d_ws;
  size_t off = 0;
  auto alloc = [&](size_t bytes) { char* p = ws + off; off = (off + bytes + 255) & ~(size_t)255; return p; };

  unsigned short* hb0 = (unsigned short*)alloc(B_ * H_ * 2);   // 256 KB (zeroed: h0 = 0)
  unsigned short* hb1 = (unsigned short*)alloc(B_ * H_ * 2);   // 256 KB
  unsigned int*   ctr = (unsigned int*)alloc(128 * 8 * 16 * 4); // 64 KB per-step counters
  size_t zero_bytes = off;
  unsigned short* xfr  = (unsigned short*)alloc((size_t)B_ * S_ * F_ * 2);  // 8 MB
  unsigned short* Wpk  = (unsigned short*)alloc((size_t)H_ * 2048 * 2);     // 2 MB
  unsigned short* Wipk = (unsigned short*)alloc((size_t)F_ * 2048 * 2);     // 512 KB
  float* bc    = (float*)alloc(2048 * 4);
  float* ctxg  = (float*)alloc((size_t)B_ * 1536 * 4);
  float* hid1  = (float*)alloc((size_t)B_ * H_ * 4);
  float* hfin  = (float*)alloc((size_t)B_ * H_ * 4);
  (void)ws_size; (void)in_sizes; (void)n_in; (void)out_size;

  hipMemsetAsync(d_ws, 0, zero_bytes, stream);   // h buffers + barrier counters

  prepack_w<<<648, 256, 0, stream>>>(W_hh, W_ih, b_ih, b_hh, Wpk, Wipk, bc);
  prepack_x<<<2048, 256, 0, stream>>>(x, xfr);
  ctx1_kernel<<<256, 256, 0, stream>>>(ctxin, cg_w1, cg_b1, hid1);
  ctx2_kernel<<<64, 256, 0, stream>>>(hid1, cg_w2, cg_b2, ctxg);
  lstm_kernel<<<256, 256, 0, stream>>>(xfr, Wpk, Wipk, bc, ctxg, hfin, hb0, hb1, ctr);
  post_kernel<<<256, 256, 0, stream>>>(hfin, eps, mu_w, mu_b, lv_w, lv_b,
                                       dec_w1, dec_b1, dec_w2, dec_b2, out);
}

// Round 2
// 925.125 us; speedup vs baseline: 6.3741x; 6.3741x over previous
//
#include <hip/hip_runtime.h>
#include <cstdint>
#include <cstddef>

// Sizes (fixed by the problem)
#define B_ 256
#define S_ 128
#define F_ 128
#define H_ 512
#define C_ 64
#define L_ 16
// 4H = 2048, 3H = 1536

typedef __attribute__((ext_vector_type(8))) short short8;   // 8 x bf16 (4 VGPRs) MFMA A/B frag
typedef __attribute__((ext_vector_type(4))) float f4;       // MFMA C/D frag
typedef __attribute__((ext_vector_type(4))) unsigned int u4;

__device__ __forceinline__ unsigned short f2bf(float f) {   // fp32 -> bf16 RNE
  union { float f; unsigned u; } v; v.f = f;
  unsigned r = v.u + 0x7fffu + ((v.u >> 16) & 1u);
  return (unsigned short)(r >> 16);
}
__device__ __forceinline__ float sigmoid_(float x) { return 1.0f / (1.0f + __expf(-x)); }
__device__ __forceinline__ float tanh_(float x) {
  x = fminf(15.f, fmaxf(-15.f, x));           // clamp: avoid inf/inf
  float e = __expf(2.f * x);
  return (e - 1.f) / (e + 1.f);
}

// ---------------------------------------------------------------------------
// Pre-pack W_hh / W_ih into MFMA B-fragment order (bf16) + combined bias.
// ---------------------------------------------------------------------------
__global__ void prepack_w(const float* __restrict__ W_hh, const float* __restrict__ W_ih,
                          const float* __restrict__ b_ih, const float* __restrict__ b_hh,
                          unsigned short* __restrict__ Wpk, unsigned short* __restrict__ Wipk,
                          float* __restrict__ bc) {
  int t = blockIdx.x * blockDim.x + threadIdx.x;
  if (t < 131072) {                      // W_hh: 32 ht * 4 g * 16 kit * 64 lanes
    int lane = t & 63, row = t >> 6;
    int kit = row & 15, gh = row >> 4;
    int g = gh & 3, ht = gh >> 2;
    int k0 = kit * 32 + ((lane >> 4) << 3);
    int col = g * 512 + ht * 16 + (lane & 15);
#pragma unroll
    for (int j = 0; j < 8; j++)
      Wpk[t * 8 + j] = f2bf(W_hh[(k0 + j) * 2048 + col]);
  } else if (t < 131072 + 32768) {       // W_ih: 32 ht * 4 g * 4 kit * 64 lanes
    int t2 = t - 131072;
    int lane = t2 & 63, row = t2 >> 6;
    int kit = row & 3, gh = row >> 2;
    int g = gh & 3, ht = gh >> 2;
    int k0 = kit * 32 + ((lane >> 4) << 3);
    int col = g * 512 + ht * 16 + (lane & 15);
#pragma unroll
    for (int j = 0; j < 8; j++)
      Wipk[t2 * 8 + j] = f2bf(W_ih[(k0 + j) * 2048 + col]);
  } else if (t < 131072 + 32768 + 2048) {
    int i = t - 131072 - 32768;
    bc[i] = b_ih[i] + b_hh[i];           // b_ih + b_hh folded together
  }
}

// ---------------------------------------------------------------------------
// Pre-pack x into fragment-major bf16.
// ---------------------------------------------------------------------------
__global__ void prepack_x(const float* __restrict__ x, unsigned short* __restrict__ xfr) {
  int o8 = blockIdx.x * blockDim.x + threadIdx.x;   // 524288 chunks
  int m = o8 & 15, kb = (o8 >> 4) & 15, Rg = (o8 >> 8) & 15, s = o8 >> 12;
  int b = Rg * 16 + m;
  const float* src = x + (b * S_ + s) * F_ + kb * 8;
  unsigned short* dst = xfr + o8 * 8;
#pragma unroll
  for (int j = 0; j < 8; j++) dst[j] = f2bf(src[j]);
}

// ---------------------------------------------------------------------------
// Context gate, stage 1: hid1 = relu(context @ cg_w1 + cg_b1)   [256 x 512]
// ---------------------------------------------------------------------------
__global__ void ctx1_kernel(const float* __restrict__ context, const float* __restrict__ w1,
                            const float* __restrict__ b1, float* __restrict__ hid1) {
  __shared__ float cc[C_];
  int b = blockIdx.x, t = threadIdx.x;
  if (t < C_) cc[t] = context[b * C_ + t];
  __syncthreads();
  for (int j = t; j < H_; j += 256) {
    float acc = b1[j];
#pragma unroll 8
    for (int k = 0; k < C_; k++) acc = fmaf(cc[k], w1[k * H_ + j], acc);
    hid1[b * H_ + j] = fmaxf(acc, 0.f);
  }
}

// ---------------------------------------------------------------------------
// Context gate, stage 2: ctxg = sigmoid(hid1 @ cg_w2 + cg_b2)   [256 x 1536]
// ---------------------------------------------------------------------------
__global__ void ctx2_kernel(const float* __restrict__ hid1, const float* __restrict__ w2,
                            const float* __restrict__ b2, float* __restrict__ ctxg) {
  __shared__ float hr[4 * H_];
  int r0 = blockIdx.x * 4, t = threadIdx.x;
  for (int i = t; i < 4 * H_; i += 256) hr[i] = hid1[r0 * H_ + i];
  __syncthreads();
  float acc[4][6];
#pragma unroll
  for (int r = 0; r < 4; r++)
#pragma unroll
    for (int i = 0; i < 6; i++) acc[r][i] = 0.f;
  for (int k = 0; k < H_; k++) {
    float w[6];
#pragma unroll
    for (int i = 0; i < 6; i++) w[i] = w2[k * 1536 + t + i * 256];
#pragma unroll
    for (int r = 0; r < 4; r++) {
      float hv = hr[r * H_ + k];
#pragma unroll
      for (int i = 0; i < 6; i++) acc[r][i] = fmaf(hv, w[i], acc[r][i]);
    }
  }
#pragma unroll
  for (int r = 0; r < 4; r++)
#pragma unroll
    for (int i = 0; i < 6; i++) {
      int col = t + i * 256;
      ctxg[(r0 + r) * 1536 + col] = sigmoid_(acc[r][i] + b2[col]);
    }
}

// ---------------------------------------------------------------------------
// Persistent LSTM kernel. Grid = 256 blocks (8 batch-tiles x 32 h-col tiles).
// Cross-block h exchange via per-access cache control (sc1 write-through
// stores, sc0+sc1 bypass loads) -- NO buffer_wbl2/buffer_inv fences.
// Release = __syncthreads' vmcnt(0) drain; counter = relaxed agent atomics.
// ---------------------------------------------------------------------------
__global__ void __launch_bounds__(256) lstm_kernel(
    const unsigned short* __restrict__ xfr, const unsigned short* __restrict__ Wpk,
    const unsigned short* __restrict__ Wipk, const float* __restrict__ bc,
    const float* __restrict__ ctxg, float* __restrict__ hfinal,
    unsigned short* __restrict__ hb0, unsigned short* __restrict__ hb1,
    unsigned int* __restrict__ ctr) {
  __shared__ __align__(16) unsigned short lds_h[16384];  // 2R x 16kit x 512  (32 KB)
  __shared__ __align__(16) unsigned short lds_x[4096];   // 2R x 4kit x 512   (8 KB)
  __shared__ float lds_g[128 * 17];                      // stride 17: no bank conflict

  int tid = threadIdx.x, lane = tid & 63, wid = tid >> 6;
  int bt = blockIdx.x >> 5, ht = blockIdx.x & 31;

  // --- prologue: resident weight fragments (coalesced 16B/lane loads) ---
  short8 wf[16], wfi[4];
  {
    const short8* wp = (const short8*)Wpk + (ht * 4 + wid) * 16 * 64 + lane;
#pragma unroll
    for (int kit = 0; kit < 16; kit++) wf[kit] = wp[kit * 64];
    const short8* wip = (const short8*)Wipk + (ht * 4 + wid) * 4 * 64 + lane;
#pragma unroll
    for (int kit = 0; kit < 4; kit++) wfi[kit] = wip[kit * 64];
  }

  // --- per-thread elementwise state: 2 adjacent j's (one packed uint store) ---
  int bl = tid >> 3, jl0 = (tid & 7) * 2;       // bl in [0,32), jl0 even
  int bglob = bt * 32 + bl;
  int j0 = ht * 16 + jl0;
  float cst[2] = {0.f, 0.f};
  float ci_[2], cf_[2], co_[2], bi_[2], bf_[2], bg_[2], bo_[2];
#pragma unroll
  for (int p = 0; p < 2; p++) {
    int j = j0 + p;
    ci_[p] = ctxg[bglob * 1536 + j];
    cf_[p] = ctxg[bglob * 1536 + 512 + j];
    co_[p] = ctxg[bglob * 1536 + 1024 + j];
    bi_[p] = bc[j]; bf_[p] = bc[512 + j]; bg_[p] = bc[1024 + j]; bo_[p] = bc[1536 + j];
  }
  // fragment-major short offset of (bglob, j0); /2 -> packed uint offset
  int hoff2 = (((bt * 2 + (bl >> 4)) * 64 + ht * 2 + (jl0 >> 3)) * 128
               + (bl & 15) * 8 + (jl0 & 7)) >> 1;

  for (int t = 0; t < S_; t++) {
    const unsigned short* hread = (t & 1) ? hb1 : hb0;   // double buffer
    unsigned short* hwrite = (t & 1) ? hb0 : hb1;

    // --- stage x-tile (cached loads: read-only, L2-friendly) ---
#pragma unroll
    for (int i = 0; i < 2; i++) {
      int c = wid * 2 + i, R = c >> 2, kit = c & 3;
      u4 d = *(const u4*)(xfr + (size_t)(((t * 16) + bt * 2 + R) * 16 + kit * 4) * 128 + lane * 8);
      *(u4*)(lds_x + (R * 4 + kit) * 512 + lane * 8) = d;
    }
    // --- stage h-tile via L1/L2-bypass dword loads (fresh from L3) ---
    {
      u4 tmp[8];
#pragma unroll
      for (int i = 0; i < 8; i++) {
        int c = wid * 8 + i, R = c >> 4, kit = c & 15;
        const unsigned int* src = (const unsigned int*)hread
            + (bt * 2 + R) * 4096 + kit * 256 + lane * 4;
        tmp[i].x = __hip_atomic_load(src + 0, __ATOMIC_RELAXED, __HIP_MEMORY_SCOPE_AGENT);
        tmp[i].y = __hip_atomic_load(src + 1, __ATOMIC_RELAXED, __HIP_MEMORY_SCOPE_AGENT);
        tmp[i].z = __hip_atomic_load(src + 2, __ATOMIC_RELAXED, __HIP_MEMORY_SCOPE_AGENT);
        tmp[i].w = __hip_atomic_load(src + 3, __ATOMIC_RELAXED, __HIP_MEMORY_SCOPE_AGENT);
      }
#pragma unroll
      for (int i = 0; i < 8; i++) {
        int c = wid * 8 + i, R = c >> 4, kit = c & 15;
        *(u4*)(lds_h + R * 8192 + kit * 512 + lane * 8) = tmp[i];
      }
    }
    __syncthreads();

    // --- MFMA: gates(32x64) = x_t(32x128)@Wih_slice + h(32x512)@Whh_slice ---
    f4 acc0 = {0.f, 0.f, 0.f, 0.f}, acc1 = {0.f, 0.f, 0.f, 0.f};
#pragma unroll
    for (int kit = 0; kit < 4; kit++) {
      short8 a0 = *(const short8*)(lds_x + kit * 512 + lane * 8);
      short8 a1 = *(const short8*)(lds_x + 2048 + kit * 512 + lane * 8);
      acc0 = __builtin_amdgcn_mfma_f32_16x16x32_bf16(a0, wfi[kit], acc0, 0, 0, 0);
      acc1 = __builtin_amdgcn_mfma_f32_16x16x32_bf16(a1, wfi[kit], acc1, 0, 0, 0);
    }
#pragma unroll
    for (int kit = 0; kit < 16; kit++) {
      short8 a0 = *(const short8*)(lds_h + kit * 512 + lane * 8);
      short8 a1 = *(const short8*)(lds_h + 8192 + kit * 512 + lane * 8);
      acc0 = __builtin_amdgcn_mfma_f32_16x16x32_bf16(a0, wf[kit], acc0, 0, 0, 0);
      acc1 = __builtin_amdgcn_mfma_f32_16x16x32_bf16(a1, wf[kit], acc1, 0, 0, 0);
    }

    // --- cross-gate combine: wave g publishes its gate block to LDS ---
    {
      int q = lane >> 4, n = lane & 15;
#pragma unroll
      for (int r = 0; r < 4; r++) {
        lds_g[(wid * 32 + q * 4 + r) * 17 + n] = acc0[r];        // rows 0..15
        lds_g[(wid * 32 + 16 + q * 4 + r) * 17 + n] = acc1[r];   // rows 16..31
      }
    }
    __syncthreads();

    // --- elementwise LSTM cell update (fp32), packed bf16x2 write-through ---
    {
      float hv[2];
#pragma unroll
      for (int p = 0; p < 2; p++) {
        int jl = jl0 + p;
        float gi = lds_g[(0 * 32 + bl) * 17 + jl] + bi_[p];
        float gf = lds_g[(1 * 32 + bl) * 17 + jl] + bf_[p];
        float gg = lds_g[(2 * 32 + bl) * 17 + jl] + bg_[p];
        float go = lds_g[(3 * 32 + bl) * 17 + jl] + bo_[p];
        float iv = ci_[p] * sigmoid_(gi);
        float fv = cf_[p] * sigmoid_(gf);
        float ov = co_[p] * sigmoid_(go);
        float gv = tanh_(gg);
        float c = fv * cst[p] + iv * gv;
        cst[p] = c;
        hv[p] = ov * tanh_(c);
      }
      unsigned int packed = (unsigned)f2bf(hv[0]) | ((unsigned)f2bf(hv[1]) << 16);
      __hip_atomic_store((unsigned int*)hwrite + hoff2, packed,
                         __ATOMIC_RELAXED, __HIP_MEMORY_SCOPE_AGENT);
      if (t == S_ - 1) {
        hfinal[bglob * H_ + j0] = hv[0];
        hfinal[bglob * H_ + j0 + 1] = hv[1];
      }
    }

    // --- inter-block barrier (per batch-tile group of 32 blocks) ---
    if (t < S_ - 1) {
      // __syncthreads drains vmcnt(0) per-thread before s_barrier => all sc1
      // write-through h stores are globally visible. No wbl2/inv needed.
      __syncthreads();
      if (tid == 0) {
        unsigned int* c32 = ctr + (t * 8 + bt) * 16;   // 64B-spaced per-step counter
        __hip_atomic_fetch_add(c32, 1u, __ATOMIC_RELAXED, __HIP_MEMORY_SCOPE_AGENT);
        while (__hip_atomic_load(c32, __ATOMIC_RELAXED, __HIP_MEMORY_SCOPE_AGENT) < 32u) {
          __builtin_amdgcn_s_sleep(1);
        }
      }
      __syncthreads();
    }
  }
}

// ---------------------------------------------------------------------------
// VAE head: mu/lv = h@W + b, z = mu + eps*exp(0.5*lv),
// recon = relu(z@dec_w1+db1)@dec_w2+db2. One block per batch row, all fp32.
// ---------------------------------------------------------------------------
__global__ void post_kernel(const float* __restrict__ hfinal, const float* __restrict__ eps,
                            const float* __restrict__ mu_w, const float* __restrict__ mu_b,
                            const float* __restrict__ lv_w, const float* __restrict__ lv_b,
                            const float* __restrict__ dw1, const float* __restrict__ db1,
                            const float* __restrict__ dw2, const float* __restrict__ db2,
                            float* __restrict__ out) {
  __shared__ float sh[H_], sh1[H_], smu[L_], slv[L_], sz[L_];
  int b = blockIdx.x, t = threadIdx.x;
  for (int i = t; i < H_; i += 256) sh[i] = hfinal[b * H_ + i];
  __syncthreads();
  {
    int o = t >> 3, sub = t & 7, l = o & 15;   // 32 outputs x 8-lane partial dots
    const float* w = (o < 16) ? mu_w : lv_w;
    float acc = 0.f;
    int k0 = sub * 64;
#pragma unroll 8
    for (int k = k0; k < k0 + 64; k++) acc = fmaf(sh[k], w[k * L_ + l], acc);
#pragma unroll
    for (int d = 4; d >= 1; d >>= 1) acc += __shfl_down(acc, d, 8);
    if (sub == 0) {
      if (o < 16) { float v = acc + mu_b[l]; smu[l] = v; out[32768 + b * 16 + l] = v; }
      else        { float v = acc + lv_b[l]; slv[l] = v; out[36864 + b * 16 + l] = v; }
    }
  }
  __syncthreads();
  if (t < L_) sz[t] = smu[t] + eps[b * L_ + t] * __expf(0.5f * slv[t]);
  __syncthreads();
  for (int j = t; j < H_; j += 256) {
    float acc = db1[j];
#pragma unroll
    for (int l = 0; l < L_; l++) acc = fmaf(sz[l], dw1[l * H_ + j], acc);
    sh1[j] = fmaxf(acc, 0.f);
  }
  __syncthreads();
  if (t < F_) {
    float acc = db2[t];
    for (int k = 0; k < H_; k++) acc = fmaf(sh1[k], dw2[k * F_ + t], acc);
    out[b * F_ + t] = acc;
  }
}

// ---------------------------------------------------------------------------
extern "C" void kernel_launch(void* const* d_in, const int* in_sizes, int n_in,
                              void* d_out, int out_size, void* d_ws, size_t ws_size,
                              hipStream_t stream) {
  const float* x      = (const float*)d_in[0];
  const float* ctxin  = (const float*)d_in[1];
  const float* eps    = (const float*)d_in[2];
  const float* W_ih   = (const float*)d_in[3];
  const float* b_ih   = (const float*)d_in[4];
  const float* W_hh   = (const float*)d_in[5];
  const float* b_hh   = (const float*)d_in[6];
  const float* cg_w1  = (const float*)d_in[7];
  const float* cg_b1  = (const float*)d_in[8];
  const float* cg_w2  = (const float*)d_in[9];
  const float* cg_b2  = (const float*)d_in[10];
  const float* mu_w   = (const float*)d_in[11];
  const float* mu_b   = (const float*)d_in[12];
  const float* lv_w   = (const float*)d_in[13];
  const float* lv_b   = (const float*)d_in[14];
  const float* dec_w1 = (const float*)d_in[15];
  const float* dec_b1 = (const float*)d_in[16];
  const float* dec_w2 = (const float*)d_in[17];
  const float* dec_b2 = (const float*)d_in[18];
  float* out = (float*)d_out;

  char* ws = (char*)d_ws;
  size_t off = 0;
  auto alloc = [&](size_t bytes) { char* p = ws + off; off = (off + bytes + 255) & ~(size_t)255; return p; };

  unsigned short* hb0 = (unsigned short*)alloc(B_ * H_ * 2);   // 256 KB (zeroed: h0 = 0)
  unsigned short* hb1 = (unsigned short*)alloc(B_ * H_ * 2);   // 256 KB
  unsigned int*   ctr = (unsigned int*)alloc(128 * 8 * 16 * 4); // 64 KB per-step counters
  size_t zero_bytes = off;
  unsigned short* xfr  = (unsigned short*)alloc((size_t)B_ * S_ * F_ * 2);  // 8 MB
  unsigned short* Wpk  = (unsigned short*)alloc((size_t)H_ * 2048 * 2);     // 2 MB
  unsigned short* Wipk = (unsigned short*)alloc((size_t)F_ * 2048 * 2);     // 512 KB
  float* bc    = (float*)alloc(2048 * 4);
  float* ctxg  = (float*)alloc((size_t)B_ * 1536 * 4);
  float* hid1  = (float*)alloc((size_t)B_ * H_ * 4);
  float* hfin  = (float*)alloc((size_t)B_ * H_ * 4);
  (void)ws_size; (void)in_sizes; (void)n_in; (void)out_size;

  hipMemsetAsync(d_ws, 0, zero_bytes, stream);   // h buffers + barrier counters

  prepack_w<<<648, 256, 0, stream>>>(W_hh, W_ih, b_ih, b_hh, Wpk, Wipk, bc);
  prepack_x<<<2048, 256, 0, stream>>>(x, xfr);
  ctx1_kernel<<<256, 256, 0, stream>>>(ctxin, cg_w1, cg_b1, hid1);
  ctx2_kernel<<<64, 256, 0, stream>>>(hid1, cg_w2, cg_b2, ctxg);
  lstm_kernel<<<256, 256, 0, stream>>>(xfr, Wpk, Wipk, bc, ctxg, hfin, hb0, hb1, ctr);
  post_kernel<<<256, 256, 0, stream>>>(hfin, eps, mu_w, mu_b, lv_w, lv_b,
                                       dec_w1, dec_b1, dec_w2, dec_b2, out);
}

// Round 3
// 569.837 us; speedup vs baseline: 10.3483x; 1.6235x over previous
//
#include <hip/hip_runtime.h>
#include <cstdint>
#include <cstddef>

// Sizes (fixed by the problem)
#define B_ 256
#define S_ 128
#define F_ 128
#define H_ 512
#define C_ 64
#define L_ 16
// 4H = 2048, 3H = 1536

typedef __attribute__((ext_vector_type(8))) short short8;   // 8 x bf16 (4 VGPRs) MFMA A/B frag
typedef __attribute__((ext_vector_type(4))) float f4;       // MFMA C/D frag
typedef __attribute__((ext_vector_type(4))) unsigned int u4;

__device__ __forceinline__ unsigned short f2bf(float f) {   // fp32 -> bf16 RNE
  union { float f; unsigned u; } v; v.f = f;
  unsigned r = v.u + 0x7fffu + ((v.u >> 16) & 1u);
  return (unsigned short)(r >> 16);
}
__device__ __forceinline__ float sigmoid_(float x) { return 1.0f / (1.0f + __expf(-x)); }
__device__ __forceinline__ float tanh_(float x) {
  x = fminf(15.f, fmaxf(-15.f, x));           // clamp: avoid inf/inf
  float e = __expf(2.f * x);
  return (e - 1.f) / (e + 1.f);
}

// ---------------------------------------------------------------------------
// Pre-pack W_hh / W_ih into MFMA B-fragment order (bf16) + combined bias.
// ---------------------------------------------------------------------------
__global__ void prepack_w(const float* __restrict__ W_hh, const float* __restrict__ W_ih,
                          const float* __restrict__ b_ih, const float* __restrict__ b_hh,
                          unsigned short* __restrict__ Wpk, unsigned short* __restrict__ Wipk,
                          float* __restrict__ bc) {
  int t = blockIdx.x * blockDim.x + threadIdx.x;
  if (t < 131072) {                      // W_hh: 32 ht * 4 g * 16 kit * 64 lanes
    int lane = t & 63, row = t >> 6;
    int kit = row & 15, gh = row >> 4;
    int g = gh & 3, ht = gh >> 2;
    int k0 = kit * 32 + ((lane >> 4) << 3);
    int col = g * 512 + ht * 16 + (lane & 15);
#pragma unroll
    for (int j = 0; j < 8; j++)
      Wpk[t * 8 + j] = f2bf(W_hh[(k0 + j) * 2048 + col]);
  } else if (t < 131072 + 32768) {       // W_ih: 32 ht * 4 g * 4 kit * 64 lanes
    int t2 = t - 131072;
    int lane = t2 & 63, row = t2 >> 6;
    int kit = row & 3, gh = row >> 2;
    int g = gh & 3, ht = gh >> 2;
    int k0 = kit * 32 + ((lane >> 4) << 3);
    int col = g * 512 + ht * 16 + (lane & 15);
#pragma unroll
    for (int j = 0; j < 8; j++)
      Wipk[t2 * 8 + j] = f2bf(W_ih[(k0 + j) * 2048 + col]);
  } else if (t < 131072 + 32768 + 2048) {
    int i = t - 131072 - 32768;
    bc[i] = b_ih[i] + b_hh[i];           // b_ih + b_hh folded together
  }
}

// ---------------------------------------------------------------------------
// Pre-pack x into fragment-major bf16.
// ---------------------------------------------------------------------------
__global__ void prepack_x(const float* __restrict__ x, unsigned short* __restrict__ xfr) {
  int o8 = blockIdx.x * blockDim.x + threadIdx.x;   // 524288 chunks
  int m = o8 & 15, kb = (o8 >> 4) & 15, Rg = (o8 >> 8) & 15, s = o8 >> 12;
  int b = Rg * 16 + m;
  const float* src = x + (b * S_ + s) * F_ + kb * 8;
  unsigned short* dst = xfr + o8 * 8;
#pragma unroll
  for (int j = 0; j < 8; j++) dst[j] = f2bf(src[j]);
}

// ---------------------------------------------------------------------------
// Context gate, stage 1: hid1 = relu(context @ cg_w1 + cg_b1)   [256 x 512]
// ---------------------------------------------------------------------------
__global__ void ctx1_kernel(const float* __restrict__ context, const float* __restrict__ w1,
                            const float* __restrict__ b1, float* __restrict__ hid1) {
  __shared__ float cc[C_];
  int b = blockIdx.x, t = threadIdx.x;
  if (t < C_) cc[t] = context[b * C_ + t];
  __syncthreads();
  for (int j = t; j < H_; j += 256) {
    float acc = b1[j];
#pragma unroll 8
    for (int k = 0; k < C_; k++) acc = fmaf(cc[k], w1[k * H_ + j], acc);
    hid1[b * H_ + j] = fmaxf(acc, 0.f);
  }
}

// ---------------------------------------------------------------------------
// Context gate, stage 2: ctxg = sigmoid(hid1 @ cg_w2 + cg_b2)   [256 x 1536]
// ---------------------------------------------------------------------------
__global__ void ctx2_kernel(const float* __restrict__ hid1, const float* __restrict__ w2,
                            const float* __restrict__ b2, float* __restrict__ ctxg) {
  __shared__ float hr[4 * H_];
  int r0 = blockIdx.x * 4, t = threadIdx.x;
  for (int i = t; i < 4 * H_; i += 256) hr[i] = hid1[r0 * H_ + i];
  __syncthreads();
  float acc[4][6];
#pragma unroll
  for (int r = 0; r < 4; r++)
#pragma unroll
    for (int i = 0; i < 6; i++) acc[r][i] = 0.f;
  for (int k = 0; k < H_; k++) {
    float w[6];
#pragma unroll
    for (int i = 0; i < 6; i++) w[i] = w2[k * 1536 + t + i * 256];
#pragma unroll
    for (int r = 0; r < 4; r++) {
      float hv = hr[r * H_ + k];
#pragma unroll
      for (int i = 0; i < 6; i++) acc[r][i] = fmaf(hv, w[i], acc[r][i]);
    }
  }
#pragma unroll
  for (int r = 0; r < 4; r++)
#pragma unroll
    for (int i = 0; i < 6; i++) {
      int col = t + i * 256;
      ctxg[(r0 + r) * 1536 + col] = sigmoid_(acc[r][i] + b2[col]);
    }
}

// ---------------------------------------------------------------------------
// Persistent LSTM kernel. Grid = 256 blocks (8 batch-tiles x 32 h-col tiles).
// h exchange: coalesced global_load_dwordx4 / global_store_dword with
// sc0 sc1 (L1/L2-bypass to the coherent L3) via inline asm — plain loads
// coalesce at the TCC, unlike per-dword atomics (R2's bottleneck).
// Barrier: per-WAVE arrivals into 4 slice-spread counters; per-wave spin on
// the 4-counter sum == 128. No syncthreads in the barrier path.
// ---------------------------------------------------------------------------
__global__ void __launch_bounds__(256) lstm_kernel(
    const unsigned short* __restrict__ xfr, const unsigned short* __restrict__ Wpk,
    const unsigned short* __restrict__ Wipk, const float* __restrict__ bc,
    const float* __restrict__ ctxg, float* __restrict__ hfinal,
    unsigned short* __restrict__ hb0, unsigned short* __restrict__ hb1,
    unsigned int* __restrict__ ctr) {
  __shared__ __align__(16) unsigned short lds_h[16384];  // 2R x 16kit x 512  (32 KB)
  __shared__ __align__(16) unsigned short lds_x[4096];   // 2R x 4kit x 512   (8 KB)
  __shared__ float lds_g[128 * 17];                      // stride 17: conflict-light

  int tid = threadIdx.x, lane = tid & 63, wid = tid >> 6;
  int bt = blockIdx.x >> 5, ht = blockIdx.x & 31;

  // --- prologue: resident weight fragments (coalesced 16B/lane loads) ---
  short8 wf[16], wfi[4];
  {
    const short8* wp = (const short8*)Wpk + (ht * 4 + wid) * 16 * 64 + lane;
#pragma unroll
    for (int kit = 0; kit < 16; kit++) wf[kit] = wp[kit * 64];
    const short8* wip = (const short8*)Wipk + (ht * 4 + wid) * 4 * 64 + lane;
#pragma unroll
    for (int kit = 0; kit < 4; kit++) wfi[kit] = wip[kit * 64];
  }

  // --- per-thread elementwise state: 2 adjacent j's (one packed uint store) ---
  int bl = tid >> 3, jl0 = (tid & 7) * 2;       // bl in [0,32), jl0 even
  int bglob = bt * 32 + bl;
  int j0 = ht * 16 + jl0;
  float cst[2] = {0.f, 0.f};
  float ci_[2], cf_[2], co_[2], bi_[2], bf_[2], bg_[2], bo_[2];
#pragma unroll
  for (int p = 0; p < 2; p++) {
    int j = j0 + p;
    ci_[p] = ctxg[bglob * 1536 + j];
    cf_[p] = ctxg[bglob * 1536 + 512 + j];
    co_[p] = ctxg[bglob * 1536 + 1024 + j];
    bi_[p] = bc[j]; bf_[p] = bc[512 + j]; bg_[p] = bc[1024 + j]; bo_[p] = bc[1536 + j];
  }
  // fragment-major short offset of (bglob, j0); /2 -> packed uint offset
  int hoff2 = (((bt * 2 + (bl >> 4)) * 64 + ht * 2 + (jl0 >> 3)) * 128
               + (bl & 15) * 8 + (jl0 & 7)) >> 1;

  // --- stage x(0) ---
#pragma unroll
  for (int i = 0; i < 2; i++) {
    int c = wid * 2 + i, R = c >> 2, kit = c & 3;
    u4 d = *(const u4*)(xfr + (size_t)((bt * 2 + R) * 16 + kit * 4) * 128 + lane * 8);
    *(u4*)(lds_x + (R * 4 + kit) * 512 + lane * 8) = d;
  }
  __syncthreads();

  for (int t = 0; t < S_; t++) {
    const unsigned short* hread = (t & 1) ? hb1 : hb0;   // double buffer
    unsigned short* hwrite = (t & 1) ? hb0 : hb1;

    // --- per-wave spin: wait for all 128 waves of the group at step t-1 ---
    if (t > 0) {
      const unsigned int* cb = ctr + (unsigned)((t - 1) * 8 + bt) * 256;
      for (;;) {
        unsigned a = __hip_atomic_load(cb,       __ATOMIC_RELAXED, __HIP_MEMORY_SCOPE_AGENT);
        unsigned b = __hip_atomic_load(cb + 64,  __ATOMIC_RELAXED, __HIP_MEMORY_SCOPE_AGENT);
        unsigned c = __hip_atomic_load(cb + 128, __ATOMIC_RELAXED, __HIP_MEMORY_SCOPE_AGENT);
        unsigned d = __hip_atomic_load(cb + 192, __ATOMIC_RELAXED, __HIP_MEMORY_SCOPE_AGENT);
        if (a + b + c + d >= 128u) break;
      }
    }

    // --- issue h bypass loads (coalesced dwordx4, L1/L2-bypass) ---
    u4 tmp[8];
#pragma unroll
    for (int i = 0; i < 8; i++) {
      int c = wid * 8 + i, R = c >> 4, kit = c & 15;
      const unsigned int* src = (const unsigned int*)hread
          + (bt * 2 + R) * 4096 + kit * 256 + lane * 4;
      asm volatile("global_load_dwordx4 %0, %1, off sc0 sc1"
                   : "=v"(tmp[i]) : "v"(src) : "memory");
    }

    // --- x MFMAs while the h loads are in flight ---
    f4 acc0 = {0.f, 0.f, 0.f, 0.f}, acc1 = {0.f, 0.f, 0.f, 0.f};
#pragma unroll
    for (int kit = 0; kit < 4; kit++) {
      short8 a0 = *(const short8*)(lds_x + kit * 512 + lane * 8);
      short8 a1 = *(const short8*)(lds_x + 2048 + kit * 512 + lane * 8);
      acc0 = __builtin_amdgcn_mfma_f32_16x16x32_bf16(a0, wfi[kit], acc0, 0, 0, 0);
      acc1 = __builtin_amdgcn_mfma_f32_16x16x32_bf16(a1, wfi[kit], acc1, 0, 0, 0);
    }

    // --- drain h loads (values tied to the waitcnt), stage to LDS ---
    asm volatile("s_waitcnt vmcnt(0)"
                 : "+v"(tmp[0]), "+v"(tmp[1]), "+v"(tmp[2]), "+v"(tmp[3]),
                   "+v"(tmp[4]), "+v"(tmp[5]), "+v"(tmp[6]), "+v"(tmp[7])
                 :: "memory");
#pragma unroll
    for (int i = 0; i < 8; i++) {
      int c = wid * 8 + i, R = c >> 4, kit = c & 15;
      *(u4*)(lds_h + R * 8192 + kit * 512 + lane * 8) = tmp[i];
    }
    __syncthreads();

    // --- h MFMAs ---
#pragma unroll
    for (int kit = 0; kit < 16; kit++) {
      short8 a0 = *(const short8*)(lds_h + kit * 512 + lane * 8);
      short8 a1 = *(const short8*)(lds_h + 8192 + kit * 512 + lane * 8);
      acc0 = __builtin_amdgcn_mfma_f32_16x16x32_bf16(a0, wf[kit], acc0, 0, 0, 0);
      acc1 = __builtin_amdgcn_mfma_f32_16x16x32_bf16(a1, wf[kit], acc1, 0, 0, 0);
    }

    // --- cross-gate combine: wave g publishes its gate block to LDS ---
    {
      int q = lane >> 4, n = lane & 15;
#pragma unroll
      for (int r = 0; r < 4; r++) {
        lds_g[(wid * 32 + q * 4 + r) * 17 + n] = acc0[r];        // rows 0..15
        lds_g[(wid * 32 + 16 + q * 4 + r) * 17 + n] = acc1[r];   // rows 16..31
      }
    }
    __syncthreads();

    // --- elementwise LSTM cell update (fp32), packed bf16x2 write-through ---
    {
      float hv[2];
#pragma unroll
      for (int p = 0; p < 2; p++) {
        int jl = jl0 + p;
        float gi = lds_g[(0 * 32 + bl) * 17 + jl] + bi_[p];
        float gf = lds_g[(1 * 32 + bl) * 17 + jl] + bf_[p];
        float gg = lds_g[(2 * 32 + bl) * 17 + jl] + bg_[p];
        float go = lds_g[(3 * 32 + bl) * 17 + jl] + bo_[p];
        float iv = ci_[p] * sigmoid_(gi);
        float fv = cf_[p] * sigmoid_(gf);
        float ov = co_[p] * sigmoid_(go);
        float gv = tanh_(gg);
        float c = fv * cst[p] + iv * gv;
        cst[p] = c;
        hv[p] = ov * tanh_(c);
      }
      unsigned int packed = (unsigned)f2bf(hv[0]) | ((unsigned)f2bf(hv[1]) << 16);
      unsigned int* dst = (unsigned int*)hwrite + hoff2;
      asm volatile("global_store_dword %0, %1, off sc0 sc1"
                   :: "v"(dst), "v"(packed) : "memory");
      if (t == S_ - 1) {
        hfinal[bglob * H_ + j0] = hv[0];
        hfinal[bglob * H_ + j0 + 1] = hv[1];
      }
    }

    if (t < S_ - 1) {
      // --- per-wave arrive: drain own stores, then one RMW per wave ---
      asm volatile("s_waitcnt vmcnt(0)" ::: "memory");
      if (lane == 0)
        __hip_atomic_fetch_add(ctr + (unsigned)(t * 8 + bt) * 256 + wid * 64, 1u,
                               __ATOMIC_RELAXED, __HIP_MEMORY_SCOPE_AGENT);
      // --- stage x(t+1) while others arrive ---
#pragma unroll
      for (int i = 0; i < 2; i++) {
        int c = wid * 2 + i, R = c >> 2, kit = c & 3;
        u4 d = *(const u4*)(xfr + (size_t)((((t + 1) * 16) + bt * 2 + R) * 16 + kit * 4) * 128 + lane * 8);
        *(u4*)(lds_x + (R * 4 + kit) * 512 + lane * 8) = d;
      }
    }
    __syncthreads();   // gates lds_x(t+1) reads and lds_g reuse
  }
}

// ---------------------------------------------------------------------------
// VAE head: mu/lv = h@W + b, z = mu + eps*exp(0.5*lv),
// recon = relu(z@dec_w1+db1)@dec_w2+db2. One block per batch row, all fp32.
// ---------------------------------------------------------------------------
__global__ void post_kernel(const float* __restrict__ hfinal, const float* __restrict__ eps,
                            const float* __restrict__ mu_w, const float* __restrict__ mu_b,
                            const float* __restrict__ lv_w, const float* __restrict__ lv_b,
                            const float* __restrict__ dw1, const float* __restrict__ db1,
                            const float* __restrict__ dw2, const float* __restrict__ db2,
                            float* __restrict__ out) {
  __shared__ float sh[H_], sh1[H_], smu[L_], slv[L_], sz[L_];
  int b = blockIdx.x, t = threadIdx.x;
  for (int i = t; i < H_; i += 256) sh[i] = hfinal[b * H_ + i];
  __syncthreads();
  {
    int o = t >> 3, sub = t & 7, l = o & 15;   // 32 outputs x 8-lane partial dots
    const float* w = (o < 16) ? mu_w : lv_w;
    float acc = 0.f;
    int k0 = sub * 64;
#pragma unroll 8
    for (int k = k0; k < k0 + 64; k++) acc = fmaf(sh[k], w[k * L_ + l], acc);
#pragma unroll
    for (int d = 4; d >= 1; d >>= 1) acc += __shfl_down(acc, d, 8);
    if (sub == 0) {
      if (o < 16) { float v = acc + mu_b[l]; smu[l] = v; out[32768 + b * 16 + l] = v; }
      else        { float v = acc + lv_b[l]; slv[l] = v; out[36864 + b * 16 + l] = v; }
    }
  }
  __syncthreads();
  if (t < L_) sz[t] = smu[t] + eps[b * L_ + t] * __expf(0.5f * slv[t]);
  __syncthreads();
  for (int j = t; j < H_; j += 256) {
    float acc = db1[j];
#pragma unroll
    for (int l = 0; l < L_; l++) acc = fmaf(sz[l], dw1[l * H_ + j], acc);
    sh1[j] = fmaxf(acc, 0.f);
  }
  __syncthreads();
  if (t < F_) {
    float acc = db2[t];
    for (int k = 0; k < H_; k++) acc = fmaf(sh1[k], dw2[k * F_ + t], acc);
    out[b * F_ + t] = acc;
  }
}

// ---------------------------------------------------------------------------
extern "C" void kernel_launch(void* const* d_in, const int* in_sizes, int n_in,
                              void* d_out, int out_size, void* d_ws, size_t ws_size,
                              hipStream_t stream) {
  const float* x      = (const float*)d_in[0];
  const float* ctxin  = (const float*)d_in[1];
  const float* eps    = (const float*)d_in[2];
  const float* W_ih   = (const float*)d_in[3];
  const float* b_ih   = (const float*)d_in[4];
  const float* W_hh   = (const float*)d_in[5];
  const float* b_hh   = (const float*)d_in[6];
  const float* cg_w1  = (const float*)d_in[7];
  const float* cg_b1  = (const float*)d_in[8];
  const float* cg_w2  = (const float*)d_in[9];
  const float* cg_b2  = (const float*)d_in[10];
  const float* mu_w   = (const float*)d_in[11];
  const float* mu_b   = (const float*)d_in[12];
  const float* lv_w   = (const float*)d_in[13];
  const float* lv_b   = (const float*)d_in[14];
  const float* dec_w1 = (const float*)d_in[15];
  const float* dec_b1 = (const float*)d_in[16];
  const float* dec_w2 = (const float*)d_in[17];
  const float* dec_b2 = (const float*)d_in[18];
  float* out = (float*)d_out;

  char* ws = (char*)d_ws;
  size_t off = 0;
  auto alloc = [&](size_t bytes) { char* p = ws + off; off = (off + bytes + 255) & ~(size_t)255; return p; };

  unsigned short* hb0 = (unsigned short*)alloc(B_ * H_ * 2);    // 256 KB (zeroed: h0 = 0)
  unsigned short* hb1 = (unsigned short*)alloc(B_ * H_ * 2);    // 256 KB
  unsigned int*   ctr = (unsigned int*)alloc(128 * 8 * 256 * 4); // 1 MB: 4 counters/step-group, 256B apart
  size_t zero_bytes = off;
  unsigned short* xfr  = (unsigned short*)alloc((size_t)B_ * S_ * F_ * 2);  // 8 MB
  unsigned short* Wpk  = (unsigned short*)alloc((size_t)H_ * 2048 * 2);     // 2 MB
  unsigned short* Wipk = (unsigned short*)alloc((size_t)F_ * 2048 * 2);     // 512 KB
  float* bc    = (float*)alloc(2048 * 4);
  float* ctxg  = (float*)alloc((size_t)B_ * 1536 * 4);
  float* hid1  = (float*)alloc((size_t)B_ * H_ * 4);
  float* hfin  = (float*)alloc((size_t)B_ * H_ * 4);
  (void)ws_size; (void)in_sizes; (void)n_in; (void)out_size;

  hipMemsetAsync(d_ws, 0, zero_bytes, stream);   // h buffers + barrier counters

  prepack_w<<<648, 256, 0, stream>>>(W_hh, W_ih, b_ih, b_hh, Wpk, Wipk, bc);
  prepack_x<<<2048, 256, 0, stream>>>(x, xfr);
  ctx1_kernel<<<256, 256, 0, stream>>>(ctxin, cg_w1, cg_b1, hid1);
  ctx2_kernel<<<64, 256, 0, stream>>>(hid1, cg_w2, cg_b2, ctxg);
  lstm_kernel<<<256, 256, 0, stream>>>(xfr, Wpk, Wipk, bc, ctxg, hfin, hb0, hb1, ctr);
  post_kernel<<<256, 256, 0, stream>>>(hfin, eps, mu_w, mu_b, lv_w, lv_b,
                                       dec_w1, dec_b1, dec_w2, dec_b2, out);
}